// Round 10
// baseline (69.116 us; speedup 1.0000x reference)
//
#include <hip/hip_runtime.h>
#include <math.h>

#define LQ 256
#define MEML 256
#define LK 512
#define BB 4
#define NH 8
#define DM 128

#define IT 16                 // i-tile per score block
#define QSTRIDE 20            // LDS q row stride (floats): 80B, 16B-aligned

constexpr float INV2PI = 0.15915494309189535f;

// ---------------------------------------------------------------------------
// Projection (identical to R9).
// ---------------------------------------------------------------------------
__global__ __launch_bounds__(128) void proj_kernel(
    const float* __restrict__ hh, const float* __restrict__ mems,
    const float* __restrict__ Wq, const float* __restrict__ Wk,
    const float* __restrict__ paramR,
    float* __restrict__ qs, float* __restrict__ ksT)
{
    __shared__ float x[2 * 128];
    const int blk = blockIdx.x;
    const int t = threadIdx.x;
    const bool isQ = (blk < 512);                 // 512 q-blocks, 1024 k-blocks
    const int row0 = isQ ? blk * 2 : (blk - 512) * 2;
    const float* __restrict__ W = isQ ? Wq : Wk;

    #pragma unroll
    for (int r = 0; r < 2; ++r) {
        const int row = row0 + r;
        const float* src = isQ ? (hh + row * DM)
                               : ((row < MEML * BB) ? (mems + row * DM)
                                                    : (hh + (row - MEML * BB) * DM));
        x[r * 128 + t] = src[t];
    }
    __syncthreads();

    float acc0 = 0.f, acc1 = 0.f;
    const float* wrow = W + t * DM;
    #pragma unroll 8
    for (int k = 0; k < DM; k += 4) {
        const float4 w  = *(const float4*)(wrow + k);
        const float4 x0 = *(const float4*)(&x[k]);
        const float4 x1 = *(const float4*)(&x[128 + k]);
        acc0 += x0.x * w.x + x0.y * w.y + x0.z * w.z + x0.w * w.w;
        acc1 += x1.x * w.x + x1.y * w.y + x1.z * w.z + x1.w * w.w;
    }
    const int h = t >> 4, d = t & 15;
    const float rs = paramR[h] * INV2PI;
    const float v0 = acc0 * rs, v1 = acc1 * rs;
    if (isQ) {
        const int i0r = row0 >> 2, b0 = row0 & 3;
        const int i1r = (row0 + 1) >> 2, b1 = (row0 + 1) & 3;
        qs[(i0r * 32 + b0 * 8 + h) * 16 + d] = v0;
        qs[(i1r * 32 + b1 * 8 + h) * 16 + d] = v1;
    } else {
        const int j0 = (row0 + 0) >> 2, b0 = (row0 + 0) & 3;
        const int j1 = (row0 + 1) >> 2, b1 = (row0 + 1) & 3;
        ksT[((d >> 2) * LK + j0) * 128 + (b0 * 8 + h) * 4 + (d & 3)] = v0;
        ksT[((d >> 2) * LK + j1) * 128 + (b1 * 8 + h) * 4 + (d & 3)] = v1;
    }
}

// ---------------------------------------------------------------------------
// Score PROBE: R9 structure, but each output computed 4x (CSE blocked by a
// zero-cost opaque asm on the sin argument; results merged with fmaxf of
// bit-identical values). Purpose: (a) push score above the ~43us fill
// dispatches so steady-state counters appear; (b) marginal-cost bisect of
// stall-bound vs compute-bound.
// ---------------------------------------------------------------------------
__global__ __launch_bounds__(256, 4) void score_kernel(
    const float* __restrict__ qs, const float* __restrict__ ksT,
    float* __restrict__ out)
{
    __shared__ float qt[IT * 32 * QSTRIDE];       // 40 KB
    const int t = threadIdx.x;
    const int bh = t & 31;
    const int js = t >> 5;                        // 0..7
    const int i0 = blockIdx.x * IT;               // 16 i-tiles
    const int j = blockIdx.y * 8 + js;            // 64 j-tiles of 8

    constexpr float i2 = INV2PI * INV2PI;
    constexpr float i4 = i2 * i2;
    constexpr float i8 = i4 * i4;
    constexpr float C16 = i8 * i8;                // (2pi)^-16
    constexpr float EPS = 2.0e-4f * INV2PI;       // 3.18e-5 rev

    // stage q-tile: 8192 contiguous floats -> padded LDS rows
    {
        const float* src = qs + i0 * 32 * 16;
        #pragma unroll
        for (int rep = 0; rep < 8; ++rep) {
            const int c4 = rep * 256 + t;         // float4 chunk id, 0..2047
            const int row = c4 >> 2, cc = (c4 & 3) * 4;
            const float4 v = *(const float4*)(src + c4 * 4);
            *(float4*)(&qt[row * QSTRIDE + cc]) = v;
        }
    }

    // k resident in 16 VGPRs
    float k[16];
    #pragma unroll
    for (int d4 = 0; d4 < 4; ++d4) {
        const float4 v = *(const float4*)(ksT + (d4 * LK + j) * 128 + bh * 4);
        k[d4 * 4 + 0] = v.x; k[d4 * 4 + 1] = v.y;
        k[d4 * 4 + 2] = v.z; k[d4 * 4 + 3] = v.w;
    }
    __syncthreads();

    #pragma unroll 1
    for (int ii = 0; ii < IT; ++ii) {
        const float* qrow = &qt[(ii * 32 + bh) * QSTRIDE];
        float q[16];
        #pragma unroll
        for (int d4 = 0; d4 < 4; ++d4) {
            const float4 v = *(const float4*)(qrow + d4 * 4);
            q[d4 * 4 + 0] = v.x; q[d4 * 4 + 1] = v.y;
            q[d4 * 4 + 2] = v.z; q[d4 * 4 + 3] = v.w;
        }
        float rr[4];
        #pragma unroll
        for (int rep = 0; rep < 4; ++rep) {
            float pn0 = 1.f, pd0 = 1.f, pn1 = 1.f, pd1 = 1.f;
            #pragma unroll
            for (int d = 0; d < 16; ++d) {
                float u = q[d] - k[d];
                asm volatile("" : "+v"(u));       // opaque: blocks cross-rep CSE
                const float u2 = fmaxf(__builtin_fabsf(u), EPS);
                const float s = __builtin_amdgcn_sinf(u2);   // sin(2pi*u2)
                if (d < 8) { pn0 *= s; pd0 *= u2; }
                else       { pn1 *= s; pd1 *= u2; }
            }
            rr[rep] = __builtin_fabsf(pn0 * __builtin_amdgcn_rcpf(pd0)
                                    * pn1 * __builtin_amdgcn_rcpf(pd1)) * C16;
        }
        // all four rr are bit-identical; fmax tree is exact and un-CSE-able
        out[((i0 + ii) * LK + j) * 32 + bh] =
            fmaxf(fmaxf(rr[0], rr[1]), fmaxf(rr[2], rr[3]));
    }
}

extern "C" void kernel_launch(void* const* d_in, const int* in_sizes, int n_in,
                              void* d_out, int out_size, void* d_ws, size_t ws_size,
                              hipStream_t stream) {
    const float* hh     = (const float*)d_in[0];
    const float* mems   = (const float*)d_in[1];
    const float* Wq     = (const float*)d_in[2];
    const float* Wk     = (const float*)d_in[3];
    const float* paramR = (const float*)d_in[4];
    float* out = (float*)d_out;

    float* qs  = (float*)d_ws;                // 131072 floats
    float* ksT = qs + LQ * BB * DM;           // 262144 floats

    proj_kernel<<<1536, 128, 0, stream>>>(hh, mems, Wq, Wk, paramR, qs, ksT);
    score_kernel<<<dim3(LQ / IT, LK / 8), 256, 0, stream>>>(qs, ksT, out);
}

// Round 11
// 29.802 us; speedup vs baseline: 2.3192x; 2.3192x over previous
//
#include <hip/hip_runtime.h>
#include <math.h>

#define LQ 256
#define MEML 256
#define LK 512
#define BB 4
#define NH 8
#define DM 128

#define IT 8                  // i-tile per score block (20 KB LDS -> 8 blocks/CU)
#define QSTRIDE 20            // LDS q row stride (floats): 80B, 16B-aligned

constexpr float INV2PI = 0.15915494309189535f;

// ---------------------------------------------------------------------------
// Projection (R2's proven 8-row version), pre-scaled by paramR[h]/(2*pi):
//   qs[(i*4+b)*128 + h*16+d]   ( == (i*32+b*8+h)*16 + d )
//   ksT[((d>>2)*512 + j)*128 + (b*8+h)*4 + (d&3)]
// 8 rows per block -> 384 blocks; W read once per block (24 MB total).
// ---------------------------------------------------------------------------
__global__ __launch_bounds__(128) void proj_kernel(
    const float* __restrict__ hh, const float* __restrict__ mems,
    const float* __restrict__ Wq, const float* __restrict__ Wk,
    const float* __restrict__ paramR,
    float* __restrict__ qs, float* __restrict__ ksT)
{
    __shared__ float x[8 * 128];
    const int blk = blockIdx.x;
    const int t = threadIdx.x;
    const bool isQ = (blk < 128);                 // 128 q-blocks, 256 k-blocks
    const int row0 = isQ ? blk * 8 : (blk - 128) * 8;
    const float* __restrict__ W = isQ ? Wq : Wk;

    for (int r = 0; r < 8; ++r) {
        const int row = row0 + r;
        const float* src = isQ ? (hh + row * DM)
                               : ((row < MEML * BB) ? (mems + row * DM)
                                                    : (hh + (row - MEML * BB) * DM));
        x[r * 128 + t] = src[t];
    }
    __syncthreads();

    float acc[8] = {0, 0, 0, 0, 0, 0, 0, 0};
    const float* wrow = W + t * DM;
    for (int k = 0; k < DM; k += 4) {
        const float4 w = *(const float4*)(wrow + k);
        #pragma unroll
        for (int r = 0; r < 8; ++r) {
            acc[r] += x[r * 128 + k + 0] * w.x + x[r * 128 + k + 1] * w.y
                    + x[r * 128 + k + 2] * w.z + x[r * 128 + k + 3] * w.w;
        }
    }
    const int h = t >> 4, d = t & 15;
    const float rs = paramR[h] * INV2PI;
    if (isQ) {
        float* dst = qs + row0 * 128 + t;
        #pragma unroll
        for (int r = 0; r < 8; ++r) dst[r * 128] = acc[r] * rs;
    } else {
        #pragma unroll
        for (int r = 0; r < 8; ++r) {
            const int row = row0 + r;
            const int j = row >> 2, b = row & 3;
            ksT[((d >> 2) * LK + j) * 128 + (b * 8 + h) * 4 + (d & 3)] = acc[r] * rs;
        }
    }
}

// ---------------------------------------------------------------------------
// Score (R9 inner loop, occupancy-tuned): thread owns (j, bh); k[16] in
// VGPRs loaded once; q-tile (8 i) staged in LDS; zero global loads in the
// hot loop. IT=8 -> 20 KB LDS -> 8 blocks/CU; grid 2048 blocks;
// launch_bounds(256,8) -> 8 waves/SIMD at VGPR<=64.
// ---------------------------------------------------------------------------
__global__ __launch_bounds__(256, 8) void score_kernel(
    const float* __restrict__ qs, const float* __restrict__ ksT,
    float* __restrict__ out)
{
    __shared__ float qt[IT * 32 * QSTRIDE];       // 20 KB
    const int t = threadIdx.x;
    const int bh = t & 31;
    const int js = t >> 5;                        // 0..7
    const int i0 = blockIdx.x * IT;               // 32 i-tiles
    const int j = blockIdx.y * 8 + js;            // 64 j-tiles of 8

    constexpr float i2 = INV2PI * INV2PI;
    constexpr float i4 = i2 * i2;
    constexpr float i8 = i4 * i4;
    constexpr float C16 = i8 * i8;                // (2pi)^-16
    constexpr float EPS = 2.0e-4f * INV2PI;       // 3.18e-5 rev; EPS^8 > FLT_MIN

    // stage q-tile: IT*32*16 = 4096 contiguous floats -> padded LDS rows
    {
        const float* src = qs + i0 * 32 * 16;
        #pragma unroll
        for (int rep = 0; rep < 4; ++rep) {
            const int c4 = rep * 256 + t;         // float4 chunk id, 0..1023
            const int row = c4 >> 2, cc = (c4 & 3) * 4;
            const float4 v = *(const float4*)(src + c4 * 4);
            *(float4*)(&qt[row * QSTRIDE + cc]) = v;
        }
    }

    // k resident in 16 VGPRs (coalesced 512B per 32-lane group)
    float k[16];
    #pragma unroll
    for (int d4 = 0; d4 < 4; ++d4) {
        const float4 v = *(const float4*)(ksT + (d4 * LK + j) * 128 + bh * 4);
        k[d4 * 4 + 0] = v.x; k[d4 * 4 + 1] = v.y;
        k[d4 * 4 + 2] = v.z; k[d4 * 4 + 3] = v.w;
    }
    __syncthreads();

    #pragma unroll 4
    for (int ii = 0; ii < IT; ++ii) {
        const float* qrow = &qt[(ii * 32 + bh) * QSTRIDE];
        float q[16];
        #pragma unroll
        for (int d4 = 0; d4 < 4; ++d4) {
            const float4 v = *(const float4*)(qrow + d4 * 4);
            q[d4 * 4 + 0] = v.x; q[d4 * 4 + 1] = v.y;
            q[d4 * 4 + 2] = v.z; q[d4 * 4 + 3] = v.w;
        }
        float pn0 = 1.f, pd0 = 1.f, pn1 = 1.f, pd1 = 1.f;
        #pragma unroll
        for (int d = 0; d < 16; ++d) {
            const float u2 = fmaxf(__builtin_fabsf(q[d] - k[d]), EPS);
            const float s = __builtin_amdgcn_sinf(u2);   // sin(2pi*u2)
            if (d < 8) { pn0 *= s; pd0 *= u2; }
            else       { pn1 *= s; pd1 *= u2; }
        }
        const float r0 = pn0 * __builtin_amdgcn_rcpf(pd0);
        const float r1 = pn1 * __builtin_amdgcn_rcpf(pd1);
        out[((i0 + ii) * LK + j) * 32 + bh] = __builtin_fabsf(r0 * r1) * C16;
    }
}

extern "C" void kernel_launch(void* const* d_in, const int* in_sizes, int n_in,
                              void* d_out, int out_size, void* d_ws, size_t ws_size,
                              hipStream_t stream) {
    const float* hh     = (const float*)d_in[0];
    const float* mems   = (const float*)d_in[1];
    const float* Wq     = (const float*)d_in[2];
    const float* Wk     = (const float*)d_in[3];
    const float* paramR = (const float*)d_in[4];
    float* out = (float*)d_out;

    float* qs  = (float*)d_ws;                // 131072 floats
    float* ksT = qs + LQ * BB * DM;           // 262144 floats

    proj_kernel<<<384, 128, 0, stream>>>(hh, mems, Wq, Wk, paramR, qs, ksT);
    score_kernel<<<dim3(LQ / IT, LK / 8), 256, 0, stream>>>(qs, ksT, out);
}